// Round 1
// baseline (3014.933 us; speedup 1.0000x reference)
//
#include <hip/hip_runtime.h>

#define N_HITS 30000
#define N_EDGES 90000
#define N_SPS 30000
#define HD 128
#define NCLS 5

// ---------------- encoder: h = relu(x @ W_enc + b_enc), x:[N,4] ----------------
__global__ void enc_kernel(const float* __restrict__ xu, const float* __restrict__ xv,
                           const float* __restrict__ xy, const float* __restrict__ W,
                           const float* __restrict__ b, float* __restrict__ h) {
    int gid = blockIdx.x * blockDim.x + threadIdx.x;
    if (gid >= 3 * N_HITS * HD) return;
    int j = gid & (HD - 1);
    int n = (gid >> 7) % N_HITS;
    int p = gid / (N_HITS * HD);
    const float* x = (p == 0) ? xu : (p == 1) ? xv : xy;
    float acc = b[j];
#pragma unroll
    for (int k = 0; k < 4; ++k) acc = fmaf(x[n * 4 + k], W[k * HD + j], acc);
    h[gid] = fmaxf(acc, 0.f);
}

// ---------------- histogram ----------------
__global__ void hist_kernel(const int* __restrict__ idx, int* __restrict__ cnt, int n) {
    int i = blockIdx.x * blockDim.x + threadIdx.x;
    if (i < n) atomicAdd(&cnt[idx[i]], 1);
}

__global__ void inv_kernel(const int* __restrict__ cnt, float* __restrict__ inv, int n) {
    int i = blockIdx.x * blockDim.x + threadIdx.x;
    if (i < n) inv[i] = 1.0f / (float)(cnt[i] > 1 ? cnt[i] : 1);
}

// ---------------- shared tile-GEMM helper: [64 rows x K] @ [K x 128] ----------------
template <int K>
__device__ __forceinline__ void gemm_tile(const float* sA, const float* __restrict__ W,
                                          const float* __restrict__ b, int cg, int rg,
                                          float acc[8][4]) {
    float4 bb = *(const float4*)(b + (cg << 2));
#pragma unroll
    for (int r = 0; r < 8; ++r) { acc[r][0] = bb.x; acc[r][1] = bb.y; acc[r][2] = bb.z; acc[r][3] = bb.w; }
    for (int k = 0; k < K; k += 4) {
        const float* wp = W + k * HD + (cg << 2);
        float4 w0 = *(const float4*)(wp);
        float4 w1 = *(const float4*)(wp + HD);
        float4 w2 = *(const float4*)(wp + 2 * HD);
        float4 w3 = *(const float4*)(wp + 3 * HD);
#pragma unroll
        for (int r = 0; r < 8; ++r) {
            float4 a = *(const float4*)(sA + (rg * 8 + r) * K + k);
            acc[r][0] = fmaf(a.x, w0.x, acc[r][0]); acc[r][1] = fmaf(a.x, w0.y, acc[r][1]);
            acc[r][2] = fmaf(a.x, w0.z, acc[r][2]); acc[r][3] = fmaf(a.x, w0.w, acc[r][3]);
            acc[r][0] = fmaf(a.y, w1.x, acc[r][0]); acc[r][1] = fmaf(a.y, w1.y, acc[r][1]);
            acc[r][2] = fmaf(a.y, w1.z, acc[r][2]); acc[r][3] = fmaf(a.y, w1.w, acc[r][3]);
            acc[r][0] = fmaf(a.z, w2.x, acc[r][0]); acc[r][1] = fmaf(a.z, w2.y, acc[r][1]);
            acc[r][2] = fmaf(a.z, w2.z, acc[r][2]); acc[r][3] = fmaf(a.z, w2.w, acc[r][3]);
            acc[r][0] = fmaf(a.w, w3.x, acc[r][0]); acc[r][1] = fmaf(a.w, w3.y, acc[r][1]);
            acc[r][2] = fmaf(a.w, w3.z, acc[r][2]); acc[r][3] = fmaf(a.w, w3.w, acc[r][3]);
        }
    }
}

// ---------------- edge message MLP, fused 2-layer + scatter-mean ----------------
// per block: 64 edges x 128 cols. A = [h[dst] | h[src]] (256), m = relu(A@W1+b1)@W2+b2,
// atomicAdd(agg[dst], m * inv_dst[dst])
__launch_bounds__(256)
__global__ void edge_kernel(const float* __restrict__ h, const int* __restrict__ eu,
                            const int* __restrict__ ev, const int* __restrict__ ey,
                            const float* __restrict__ W1, const float* __restrict__ b1,
                            const float* __restrict__ W2, const float* __restrict__ b2,
                            const float* __restrict__ invd, float* __restrict__ agg) {
    int p = blockIdx.y;
    const int* e = (p == 0) ? eu : (p == 1) ? ev : ey;
    const float* hp = h + (size_t)p * N_HITS * HD;
    float* aggp = agg + (size_t)p * N_HITS * HD;
    const float* invp = invd + p * N_HITS;

    __shared__ int sSrc[64], sDst[64];
    __shared__ float sInv[64];
    __shared__ float sA[64 * 256];

    int t = threadIdx.x;
    int e0 = blockIdx.x * 64;
    if (t < 64) {
        int ei = e0 + t;
        int s = 0, d = 0; float iv = 0.f;
        if (ei < N_EDGES) { s = e[ei]; d = e[N_EDGES + ei]; iv = invp[d]; }
        sSrc[t] = s; sDst[t] = d; sInv[t] = iv;
    }
    __syncthreads();
    // stage A tile: row r = [h[dst] (128) | h[src] (128)]
    for (int i = t; i < 64 * 64; i += 256) {
        int row = i >> 6, q = i & 63;
        int node = (q < 32) ? sDst[row] : sSrc[row];
        int qq = q & 31;
        float4 v = *(const float4*)(hp + (size_t)node * HD + qq * 4);
        *(float4*)(&sA[row * 256 + q * 4]) = v;
    }
    __syncthreads();

    int cg = t & 31, rg = t >> 5;
    float acc[8][4];
    gemm_tile<256>(sA, W1, b1, cg, rg, acc);
    __syncthreads();
    // relu(m) -> LDS (reusing sA front)
#pragma unroll
    for (int r = 0; r < 8; ++r) {
        float4 v;
        v.x = fmaxf(acc[r][0], 0.f); v.y = fmaxf(acc[r][1], 0.f);
        v.z = fmaxf(acc[r][2], 0.f); v.w = fmaxf(acc[r][3], 0.f);
        *(float4*)(&sA[(rg * 8 + r) * 128 + cg * 4]) = v;
    }
    __syncthreads();
    gemm_tile<128>(sA, W2, b2, cg, rg, acc);
    // scatter-add (mean via pre-scaled inv count)
#pragma unroll
    for (int r = 0; r < 8; ++r) {
        int row = rg * 8 + r;
        int ei = e0 + row;
        if (ei < N_EDGES) {
            float s = sInv[row];
            float* dst = aggp + (size_t)sDst[row] * HD + cg * 4;
            unsafeAtomicAdd(dst + 0, acc[r][0] * s);
            unsafeAtomicAdd(dst + 1, acc[r][1] * s);
            unsafeAtomicAdd(dst + 2, acc[r][2] * s);
            unsafeAtomicAdd(dst + 3, acc[r][3] * s);
        }
    }
}

// ---------------- node update: h += relu([h | aux] @ W + b) ----------------
__launch_bounds__(256)
__global__ void update_kernel(float* __restrict__ h, const float* __restrict__ aux,
                              const float* __restrict__ W, const float* __restrict__ b) {
    int p = blockIdx.y;
    float* hp = h + (size_t)p * N_HITS * HD;
    const float* ap = aux + (size_t)p * N_HITS * HD;
    __shared__ float sA[64 * 256];
    int t = threadIdx.x;
    int n0 = blockIdx.x * 64;
    for (int i = t; i < 64 * 64; i += 256) {
        int row = i >> 6, q = i & 63, qq = q & 31;
        int n = n0 + row; if (n >= N_HITS) n = N_HITS - 1;
        const float* src = (q < 32) ? (hp + (size_t)n * HD) : (ap + (size_t)n * HD);
        *(float4*)(&sA[row * 256 + q * 4]) = *(const float4*)(src + qq * 4);
    }
    __syncthreads();
    int cg = t & 31, rg = t >> 5;
    float acc[8][4];
    gemm_tile<256>(sA, W, b, cg, rg, acc);
#pragma unroll
    for (int r = 0; r < 8; ++r) {
        int n = n0 + rg * 8 + r;
        if (n < N_HITS) {
            float* dst = hp + (size_t)n * HD + cg * 4;
            float4 old = *(float4*)dst;
            old.x += fmaxf(acc[r][0], 0.f); old.y += fmaxf(acc[r][1], 0.f);
            old.z += fmaxf(acc[r][2], 0.f); old.w += fmaxf(acc[r][3], 0.f);
            *(float4*)dst = old;
        }
    }
}

// ---------------- nexus scatter: sp[spid] += h[hit] * inv_sp[spid] ----------------
__global__ void nx_scatter_kernel(const float* __restrict__ h, const int* __restrict__ nu,
                                  const int* __restrict__ nv, const int* __restrict__ ny,
                                  const float* __restrict__ invsp, float* __restrict__ sp) {
    int gt = blockIdx.x * blockDim.x + threadIdx.x;
    int wid = gt >> 6;
    int lane = gt & 63;
    if (wid >= 3 * N_SPS) return;
    int p = wid / N_SPS;
    int i = wid - p * N_SPS;
    const int* nx = (p == 0) ? nu : (p == 1) ? nv : ny;
    int hit = nx[i];
    int spid = nx[N_SPS + i];
    float s = invsp[p * N_SPS + spid];
    const float* hrow = h + (size_t)(p * N_HITS + hit) * HD;
    float* srow = sp + (size_t)spid * HD;
    unsafeAtomicAdd(&srow[lane], hrow[lane] * s);
    unsafeAtomicAdd(&srow[lane + 64], hrow[lane + 64] * s);
}

// ---------------- sp = relu(sp @ W_sp + b_sp), in-place ----------------
__launch_bounds__(256)
__global__ void sp_gemm_kernel(float* __restrict__ sp, const float* __restrict__ W,
                               const float* __restrict__ b) {
    __shared__ float sA[64 * 128];
    int t = threadIdx.x;
    int n0 = blockIdx.x * 64;
    for (int i = t; i < 64 * 32; i += 256) {
        int row = i >> 5, q = i & 31;
        int n = n0 + row; if (n >= N_SPS) n = N_SPS - 1;
        *(float4*)(&sA[row * 128 + q * 4]) = *(const float4*)(sp + (size_t)n * HD + q * 4);
    }
    __syncthreads();
    int cg = t & 31, rg = t >> 5;
    float acc[8][4];
    gemm_tile<128>(sA, W, b, cg, rg, acc);
#pragma unroll
    for (int r = 0; r < 8; ++r) {
        int n = n0 + rg * 8 + r;
        if (n < N_SPS) {
            float4 v;
            v.x = fmaxf(acc[r][0], 0.f); v.y = fmaxf(acc[r][1], 0.f);
            v.z = fmaxf(acc[r][2], 0.f); v.w = fmaxf(acc[r][3], 0.f);
            *(float4*)(sp + (size_t)n * HD + cg * 4) = v;
        }
    }
}

// ---------------- back scatter: back[p][hit] += sp[spid] * inv_hit[p][hit] ----------------
__global__ void back_scatter_kernel(const float* __restrict__ sp, const int* __restrict__ nu,
                                    const int* __restrict__ nv, const int* __restrict__ ny,
                                    const float* __restrict__ invhit, float* __restrict__ back) {
    int gt = blockIdx.x * blockDim.x + threadIdx.x;
    int wid = gt >> 6;
    int lane = gt & 63;
    if (wid >= 3 * N_SPS) return;
    int p = wid / N_SPS;
    int i = wid - p * N_SPS;
    const int* nx = (p == 0) ? nu : (p == 1) ? nv : ny;
    int hit = nx[i];
    int spid = nx[N_SPS + i];
    float s = invhit[p * N_HITS + hit];
    const float* srow = sp + (size_t)spid * HD;
    float* brow = back + (size_t)(p * N_HITS + hit) * HD;
    unsafeAtomicAdd(&brow[lane], srow[lane] * s);
    unsafeAtomicAdd(&brow[lane + 64], srow[lane + 64] * s);
}

// ---------------- decoder: out = h @ W_sem + b_sem ----------------
__global__ void dec_kernel(const float* __restrict__ h, const float* __restrict__ W,
                           const float* __restrict__ b, float* __restrict__ out) {
    int gid = blockIdx.x * blockDim.x + threadIdx.x;
    if (gid >= 3 * N_HITS * NCLS) return;
    int c = gid % NCLS;
    int n = gid / NCLS;  // spans all 3 planes (h is plane-major) == out layout
    const float* hrow = h + (size_t)n * HD;
    float acc = b[c];
    for (int k = 0; k < HD; ++k) acc = fmaf(hrow[k], W[k * NCLS + c], acc);
    out[gid] = acc;
}

extern "C" void kernel_launch(void* const* d_in, const int* in_sizes, int n_in,
                              void* d_out, int out_size, void* d_ws, size_t ws_size,
                              hipStream_t stream) {
    const float* xu = (const float*)d_in[0];
    const int* eu = (const int*)d_in[1];
    const int* nu = (const int*)d_in[2];
    const float* xv = (const float*)d_in[3];
    const int* ev = (const int*)d_in[4];
    const int* nv = (const int*)d_in[5];
    const float* xy = (const float*)d_in[6];
    const int* ey = (const int*)d_in[7];
    const int* ny = (const int*)d_in[8];
    const float* W_enc = (const float*)d_in[9];
    const float* b_enc = (const float*)d_in[10];
    const float* W1 = (const float*)d_in[11];
    const float* b1 = (const float*)d_in[12];
    const float* W2 = (const float*)d_in[13];
    const float* b2 = (const float*)d_in[14];
    const float* W_upd = (const float*)d_in[15];
    const float* b_upd = (const float*)d_in[16];
    const float* W_sp = (const float*)d_in[17];
    const float* b_sp = (const float*)d_in[18];
    const float* W_nx = (const float*)d_in[19];
    const float* b_nx = (const float*)d_in[20];
    const float* W_sem = (const float*)d_in[21];
    const float* b_sem = (const float*)d_in[22];

    const size_t HN = (size_t)3 * N_HITS * HD;  // 11,520,000 floats
    float* ws = (float*)d_ws;
    float* h = ws;             // [3][N_HITS][HD]
    float* agg = h + HN;       // [3][N_HITS][HD]  (also "back" buffer)
    float* sp = agg + HN;      // [N_SPS][HD]
    float* inv = sp + (size_t)N_SPS * HD;  // [9 * 30000]: dst | sp | hit
    int* cnt = (int*)(inv + 270000);       // [9 * 30000]

    // ---- per-call constants: segment counts -> inverse means ----
    hipMemsetAsync(cnt, 0, 270000 * sizeof(int), stream);
    const int* edges[3] = {eu, ev, ey};
    const int* nxs[3] = {nu, nv, ny};
    for (int p = 0; p < 3; ++p) {
        hist_kernel<<<(N_EDGES + 255) / 256, 256, 0, stream>>>(edges[p] + N_EDGES, cnt + p * N_HITS, N_EDGES);
        hist_kernel<<<(N_SPS + 255) / 256, 256, 0, stream>>>(nxs[p] + N_SPS, cnt + 90000 + p * N_SPS, N_SPS);
        hist_kernel<<<(N_SPS + 255) / 256, 256, 0, stream>>>(nxs[p], cnt + 180000 + p * N_HITS, N_SPS);
    }
    inv_kernel<<<(270000 + 255) / 256, 256, 0, stream>>>(cnt, inv, 270000);

    // ---- encoder ----
    enc_kernel<<<(3 * N_HITS * HD + 255) / 256, 256, 0, stream>>>(xu, xv, xy, W_enc, b_enc, h);

    // ---- 3 core iterations ----
    for (int it = 0; it < 3; ++it) {
        // planar conv
        hipMemsetAsync(agg, 0, HN * sizeof(float), stream);
        edge_kernel<<<dim3((N_EDGES + 63) / 64, 3), 256, 0, stream>>>(h, eu, ev, ey, W1, b1, W2, b2, inv, agg);
        update_kernel<<<dim3((N_HITS + 63) / 64, 3), 256, 0, stream>>>(h, agg, W_upd, b_upd);
        // nexus conv
        hipMemsetAsync(sp, 0, (size_t)N_SPS * HD * sizeof(float), stream);
        nx_scatter_kernel<<<(3 * N_SPS * 64) / 256, 256, 0, stream>>>(h, nu, nv, ny, inv + 90000, sp);
        sp_gemm_kernel<<<(N_SPS + 63) / 64, 256, 0, stream>>>(sp, W_sp, b_sp);
        hipMemsetAsync(agg, 0, HN * sizeof(float), stream);
        back_scatter_kernel<<<(3 * N_SPS * 64) / 256, 256, 0, stream>>>(sp, nu, nv, ny, inv + 180000, agg);
        update_kernel<<<dim3((N_HITS + 63) / 64, 3), 256, 0, stream>>>(h, agg, W_nx, b_nx);
    }

    // ---- decoder ----
    dec_kernel<<<(3 * N_HITS * NCLS + 255) / 256, 256, 0, stream>>>(h, W_sem, b_sem, (float*)d_out);
}

// Round 2
// 1548.050 us; speedup vs baseline: 1.9476x; 1.9476x over previous
//
#include <hip/hip_runtime.h>

#define N_HITS 30000
#define N_EDGES 90000
#define N_SPS 30000
#define HD 128
#define NCLS 5

#define PADA 264  // 256 + 8 bf16 pad -> 2-way LDS bank aliasing (free)
#define PADM 136  // 128 + 8

typedef __attribute__((ext_vector_type(8))) __bf16 bf16x8;
typedef __attribute__((ext_vector_type(4))) float floatx4;

__device__ __forceinline__ uint4 cvt8_bf16(float4 a, float4 b) {
    union { __bf16 h[8]; uint4 u; } x;
    x.h[0] = (__bf16)a.x; x.h[1] = (__bf16)a.y; x.h[2] = (__bf16)a.z; x.h[3] = (__bf16)a.w;
    x.h[4] = (__bf16)b.x; x.h[5] = (__bf16)b.y; x.h[6] = (__bf16)b.z; x.h[7] = (__bf16)b.w;
    return x.u;
}

// ---------------- encoder: h = relu(x @ W_enc + b_enc), also write bf16 mirror ----------------
__global__ void enc_kernel(const float* __restrict__ xu, const float* __restrict__ xv,
                           const float* __restrict__ xy, const float* __restrict__ W,
                           const float* __restrict__ b, float* __restrict__ h,
                           __bf16* __restrict__ hb) {
    int gid = blockIdx.x * blockDim.x + threadIdx.x;
    if (gid >= 3 * N_HITS * HD) return;
    int j = gid & (HD - 1);
    int n = (gid >> 7) % N_HITS;
    int p = gid / (N_HITS * HD);
    const float* x = (p == 0) ? xu : (p == 1) ? xv : xy;
    float acc = b[j];
#pragma unroll
    for (int k = 0; k < 4; ++k) acc = fmaf(x[n * 4 + k], W[k * HD + j], acc);
    float v = fmaxf(acc, 0.f);
    h[gid] = v;
    hb[gid] = (__bf16)v;
}

// ---------------- histogram / inverse count ----------------
__global__ void hist_kernel(const int* __restrict__ idx, int* __restrict__ cnt, int n) {
    int i = blockIdx.x * blockDim.x + threadIdx.x;
    if (i < n) atomicAdd(&cnt[idx[i]], 1);
}

__global__ void inv_kernel(const int* __restrict__ cnt, float* __restrict__ inv, int n) {
    int i = blockIdx.x * blockDim.x + threadIdx.x;
    if (i < n) inv[i] = 1.0f / (float)(cnt[i] > 1 ? cnt[i] : 1);
}

// ---------------- weight pre-pack: fp32 [K][N] -> bf16 B-fragment order ----------------
// consumed as ((n_tile*KSTEPS + ks)*64 + lane)*8 + j  with
// element = W[k = ks*32 + (lane>>4)*8 + j][col = n_tile*16 + (lane&15)]
__global__ void wprep_kernel(const float* __restrict__ W1, const float* __restrict__ W2,
                             const float* __restrict__ Wu, const float* __restrict__ Wn,
                             __bf16* __restrict__ W1P, __bf16* __restrict__ W2P,
                             __bf16* __restrict__ WuP, __bf16* __restrict__ WnP) {
    int gid = blockIdx.x * blockDim.x + threadIdx.x;
    if (gid < 32768) {  // W1: 256x128
        int idx = gid;
        int j = idx & 7, lane = (idx >> 3) & 63, ks = (idx >> 9) & 7, n = (idx >> 12) & 7;
        int k = ks * 32 + (lane >> 4) * 8 + j, col = n * 16 + (lane & 15);
        W1P[idx] = (__bf16)W1[k * 128 + col];
        return;
    }
    gid -= 32768;
    if (gid < 16384) {  // W2: 128x128
        int idx = gid;
        int j = idx & 7, lane = (idx >> 3) & 63, ks = (idx >> 9) & 3, n = (idx >> 11) & 7;
        int k = ks * 32 + (lane >> 4) * 8 + j, col = n * 16 + (lane & 15);
        W2P[idx] = (__bf16)W2[k * 128 + col];
        return;
    }
    gid -= 16384;
    if (gid < 32768) {  // W_upd: 256x128
        int idx = gid;
        int j = idx & 7, lane = (idx >> 3) & 63, ks = (idx >> 9) & 7, n = (idx >> 12) & 7;
        int k = ks * 32 + (lane >> 4) * 8 + j, col = n * 16 + (lane & 15);
        WuP[idx] = (__bf16)Wu[k * 128 + col];
        return;
    }
    gid -= 32768;
    if (gid < 32768) {  // W_nx: 256x128
        int idx = gid;
        int j = idx & 7, lane = (idx >> 3) & 63, ks = (idx >> 9) & 7, n = (idx >> 12) & 7;
        int k = ks * 32 + (lane >> 4) * 8 + j, col = n * 16 + (lane & 15);
        WnP[idx] = (__bf16)Wn[k * 128 + col];
    }
}

// ---------------- edge MLP (MFMA), fused 2 layers + atomic scatter-mean ----------------
// block = 256 thr (4 waves) x 64 edges x 128 cols; wave w owns rows [w*16, w*16+16)
__launch_bounds__(256)
__global__ void edge_mfma_kernel(const __bf16* __restrict__ hb, const int* __restrict__ eu,
                                 const int* __restrict__ ev, const int* __restrict__ ey,
                                 const __bf16* __restrict__ W1P, const float* __restrict__ b1,
                                 const __bf16* __restrict__ W2P, const float* __restrict__ b2,
                                 const float* __restrict__ invd, float* __restrict__ agg) {
    int p = blockIdx.y;
    const int* e = (p == 0) ? eu : (p == 1) ? ev : ey;
    const __bf16* hbp = hb + (size_t)p * N_HITS * HD;
    float* aggp = agg + (size_t)p * N_HITS * HD;
    const float* invp = invd + p * N_HITS;

    __shared__ __bf16 sA[64 * PADA];
    __shared__ __bf16 sM[64 * PADM];
    __shared__ int sSrc[64], sDst[64];
    __shared__ float sInv[64];

    int t = threadIdx.x;
    int e0 = blockIdx.x * 64;
    if (t < 64) {
        int ei = e0 + t;
        int s = 0, d = 0; float iv = 0.f;
        if (ei < N_EDGES) { s = e[ei]; d = e[N_EDGES + ei]; iv = invp[d]; }
        sSrc[t] = s; sDst[t] = d; sInv[t] = iv;
    }
    __syncthreads();
    // stage A tile (bf16): row = [hb[dst] (128) | hb[src] (128)], 32 x 16B chunks/row
    for (int i = t; i < 2048; i += 256) {
        int row = i >> 5, c = i & 31;
        int node = (c < 16) ? sDst[row] : sSrc[row];
        uint4 v = ((const uint4*)(hbp + (size_t)node * HD))[c & 15];
        *(uint4*)&sA[row * PADA + c * 8] = v;
    }
    __syncthreads();

    int lane = t & 63;
    int wave = t >> 6;
    int r0 = wave * 16;
    int lcol = lane & 15;
    int quad = lane >> 4;

    // ---- layer 1: [64x256] @ [256x128], acc init = b1 ----
    floatx4 acc[8];
#pragma unroll
    for (int n = 0; n < 8; ++n) { float bv = b1[n * 16 + lcol]; acc[n] = (floatx4){bv, bv, bv, bv}; }
    const bf16x8* w1p = (const bf16x8*)W1P;
#pragma unroll
    for (int ks = 0; ks < 8; ++ks) {
        bf16x8 a = *(const bf16x8*)&sA[(r0 + lcol) * PADA + ks * 32 + quad * 8];
#pragma unroll
        for (int n = 0; n < 8; ++n) {
            bf16x8 bfr = w1p[(n * 8 + ks) * 64 + lane];
            acc[n] = __builtin_amdgcn_mfma_f32_16x16x32_bf16(a, bfr, acc[n], 0, 0, 0);
        }
    }
    // relu -> bf16 -> LDS (wave-private rows; C layout: col=lane&15, row=quad*4+reg)
#pragma unroll
    for (int n = 0; n < 8; ++n) {
#pragma unroll
        for (int r = 0; r < 4; ++r) {
            int row = r0 + quad * 4 + r;
            sM[row * PADM + n * 16 + lcol] = (__bf16)fmaxf(acc[n][r], 0.f);
        }
    }
    // ---- layer 2: [64x128] @ [128x128], acc init = b2 ----
    floatx4 acc2[8];
#pragma unroll
    for (int n = 0; n < 8; ++n) { float bv = b2[n * 16 + lcol]; acc2[n] = (floatx4){bv, bv, bv, bv}; }
    const bf16x8* w2p = (const bf16x8*)W2P;
#pragma unroll
    for (int ks = 0; ks < 4; ++ks) {
        bf16x8 a = *(const bf16x8*)&sM[(r0 + lcol) * PADM + ks * 32 + quad * 8];
#pragma unroll
        for (int n = 0; n < 8; ++n) {
            bf16x8 bfr = w2p[(n * 4 + ks) * 64 + lane];
            acc2[n] = __builtin_amdgcn_mfma_f32_16x16x32_bf16(a, bfr, acc2[n], 0, 0, 0);
        }
    }
    // scatter-add (mean via pre-scaled inv; tail rows have inv=0)
#pragma unroll
    for (int n = 0; n < 8; ++n) {
#pragma unroll
        for (int r = 0; r < 4; ++r) {
            int row = r0 + quad * 4 + r;
            float v = acc2[n][r] * sInv[row];
            unsafeAtomicAdd(&aggp[(size_t)sDst[row] * HD + n * 16 + lcol], v);
        }
    }
}

// ---------------- node update (MFMA): h += relu([h | aux] @ W + b), writes bf16 mirror ----------------
__launch_bounds__(256)
__global__ void update_mfma_kernel(float* __restrict__ h, __bf16* __restrict__ hb,
                                   const float* __restrict__ aux,
                                   const __bf16* __restrict__ WP, const float* __restrict__ b) {
    int p = blockIdx.y;
    float* hp = h + (size_t)p * N_HITS * HD;
    __bf16* hbp = hb + (size_t)p * N_HITS * HD;
    const float* ap = aux + (size_t)p * N_HITS * HD;

    __shared__ __bf16 sA[64 * PADA];
    int t = threadIdx.x;
    int n0 = blockIdx.x * 64;
    // stage h half (already bf16)
    for (int i = t; i < 1024; i += 256) {
        int row = i >> 4, c = i & 15;
        int n = n0 + row; if (n >= N_HITS) n = N_HITS - 1;
        uint4 v = ((const uint4*)(hbp + (size_t)n * HD))[c];
        *(uint4*)&sA[row * PADA + c * 8] = v;
    }
    // stage aux half (fp32 -> bf16)
    for (int i = t; i < 1024; i += 256) {
        int row = i >> 4, c = i & 15;
        int n = n0 + row; if (n >= N_HITS) n = N_HITS - 1;
        const float4* src = (const float4*)(ap + (size_t)n * HD + c * 8);
        *(uint4*)&sA[row * PADA + 128 + c * 8] = cvt8_bf16(src[0], src[1]);
    }
    __syncthreads();

    int lane = t & 63;
    int wave = t >> 6;
    int r0 = wave * 16;
    int lcol = lane & 15;
    int quad = lane >> 4;

    floatx4 acc[8];
#pragma unroll
    for (int n = 0; n < 8; ++n) { float bv = b[n * 16 + lcol]; acc[n] = (floatx4){bv, bv, bv, bv}; }
    const bf16x8* wp = (const bf16x8*)WP;
#pragma unroll
    for (int ks = 0; ks < 8; ++ks) {
        bf16x8 a = *(const bf16x8*)&sA[(r0 + lcol) * PADA + ks * 32 + quad * 8];
#pragma unroll
        for (int n = 0; n < 8; ++n) {
            bf16x8 bfr = wp[(n * 8 + ks) * 64 + lane];
            acc[n] = __builtin_amdgcn_mfma_f32_16x16x32_bf16(a, bfr, acc[n], 0, 0, 0);
        }
    }
    // residual write (fp32) + bf16 mirror
#pragma unroll
    for (int n = 0; n < 8; ++n) {
#pragma unroll
        for (int r = 0; r < 4; ++r) {
            int m = n0 + r0 + quad * 4 + r;
            if (m < N_HITS) {
                size_t o = (size_t)m * HD + n * 16 + lcol;
                float nv = hp[o] + fmaxf(acc[n][r], 0.f);
                hp[o] = nv;
                hbp[o] = (__bf16)nv;
            }
        }
    }
}

// ---------------- fp32 tile-GEMM helper (kept for sp_gemm) ----------------
template <int K>
__device__ __forceinline__ void gemm_tile(const float* sA, const float* __restrict__ W,
                                          const float* __restrict__ b, int cg, int rg,
                                          float acc[8][4]) {
    float4 bb = *(const float4*)(b + (cg << 2));
#pragma unroll
    for (int r = 0; r < 8; ++r) { acc[r][0] = bb.x; acc[r][1] = bb.y; acc[r][2] = bb.z; acc[r][3] = bb.w; }
    for (int k = 0; k < K; k += 4) {
        const float* wp = W + k * HD + (cg << 2);
        float4 w0 = *(const float4*)(wp);
        float4 w1 = *(const float4*)(wp + HD);
        float4 w2 = *(const float4*)(wp + 2 * HD);
        float4 w3 = *(const float4*)(wp + 3 * HD);
#pragma unroll
        for (int r = 0; r < 8; ++r) {
            float4 a = *(const float4*)(sA + (rg * 8 + r) * K + k);
            acc[r][0] = fmaf(a.x, w0.x, acc[r][0]); acc[r][1] = fmaf(a.x, w0.y, acc[r][1]);
            acc[r][2] = fmaf(a.x, w0.z, acc[r][2]); acc[r][3] = fmaf(a.x, w0.w, acc[r][3]);
            acc[r][0] = fmaf(a.y, w1.x, acc[r][0]); acc[r][1] = fmaf(a.y, w1.y, acc[r][1]);
            acc[r][2] = fmaf(a.y, w1.z, acc[r][2]); acc[r][3] = fmaf(a.y, w1.w, acc[r][3]);
            acc[r][0] = fmaf(a.z, w2.x, acc[r][0]); acc[r][1] = fmaf(a.z, w2.y, acc[r][1]);
            acc[r][2] = fmaf(a.z, w2.z, acc[r][2]); acc[r][3] = fmaf(a.z, w2.w, acc[r][3]);
            acc[r][0] = fmaf(a.w, w3.x, acc[r][0]); acc[r][1] = fmaf(a.w, w3.y, acc[r][1]);
            acc[r][2] = fmaf(a.w, w3.z, acc[r][2]); acc[r][3] = fmaf(a.w, w3.w, acc[r][3]);
        }
    }
}

// ---------------- nexus scatter: sp[spid] += h[hit] * inv_sp[spid] ----------------
__global__ void nx_scatter_kernel(const float* __restrict__ h, const int* __restrict__ nu,
                                  const int* __restrict__ nv, const int* __restrict__ ny,
                                  const float* __restrict__ invsp, float* __restrict__ sp) {
    int gt = blockIdx.x * blockDim.x + threadIdx.x;
    int wid = gt >> 6;
    int lane = gt & 63;
    if (wid >= 3 * N_SPS) return;
    int p = wid / N_SPS;
    int i = wid - p * N_SPS;
    const int* nx = (p == 0) ? nu : (p == 1) ? nv : ny;
    int hit = nx[i];
    int spid = nx[N_SPS + i];
    float s = invsp[p * N_SPS + spid];
    const float* hrow = h + (size_t)(p * N_HITS + hit) * HD;
    float* srow = sp + (size_t)spid * HD;
    unsafeAtomicAdd(&srow[lane], hrow[lane] * s);
    unsafeAtomicAdd(&srow[lane + 64], hrow[lane + 64] * s);
}

// ---------------- sp = relu(sp @ W_sp + b_sp), in-place ----------------
__launch_bounds__(256)
__global__ void sp_gemm_kernel(float* __restrict__ sp, const float* __restrict__ W,
                               const float* __restrict__ b) {
    __shared__ float sA[64 * 128];
    int t = threadIdx.x;
    int n0 = blockIdx.x * 64;
    for (int i = t; i < 64 * 32; i += 256) {
        int row = i >> 5, q = i & 31;
        int n = n0 + row; if (n >= N_SPS) n = N_SPS - 1;
        *(float4*)(&sA[row * 128 + q * 4]) = *(const float4*)(sp + (size_t)n * HD + q * 4);
    }
    __syncthreads();
    int cg = t & 31, rg = t >> 5;
    float acc[8][4];
    gemm_tile<128>(sA, W, b, cg, rg, acc);
#pragma unroll
    for (int r = 0; r < 8; ++r) {
        int n = n0 + rg * 8 + r;
        if (n < N_SPS) {
            float4 v;
            v.x = fmaxf(acc[r][0], 0.f); v.y = fmaxf(acc[r][1], 0.f);
            v.z = fmaxf(acc[r][2], 0.f); v.w = fmaxf(acc[r][3], 0.f);
            *(float4*)(sp + (size_t)n * HD + cg * 4) = v;
        }
    }
}

// ---------------- back scatter: back[p][hit] += sp[spid] * inv_hit[p][hit] ----------------
__global__ void back_scatter_kernel(const float* __restrict__ sp, const int* __restrict__ nu,
                                    const int* __restrict__ nv, const int* __restrict__ ny,
                                    const float* __restrict__ invhit, float* __restrict__ back) {
    int gt = blockIdx.x * blockDim.x + threadIdx.x;
    int wid = gt >> 6;
    int lane = gt & 63;
    if (wid >= 3 * N_SPS) return;
    int p = wid / N_SPS;
    int i = wid - p * N_SPS;
    const int* nx = (p == 0) ? nu : (p == 1) ? nv : ny;
    int hit = nx[i];
    int spid = nx[N_SPS + i];
    float s = invhit[p * N_HITS + hit];
    const float* srow = sp + (size_t)spid * HD;
    float* brow = back + (size_t)(p * N_HITS + hit) * HD;
    unsafeAtomicAdd(&brow[lane], srow[lane] * s);
    unsafeAtomicAdd(&brow[lane + 64], srow[lane + 64] * s);
}

// ---------------- decoder: out = h @ W_sem + b_sem ----------------
__global__ void dec_kernel(const float* __restrict__ h, const float* __restrict__ W,
                           const float* __restrict__ b, float* __restrict__ out) {
    int gid = blockIdx.x * blockDim.x + threadIdx.x;
    if (gid >= 3 * N_HITS * NCLS) return;
    int c = gid % NCLS;
    int n = gid / NCLS;
    const float* hrow = h + (size_t)n * HD;
    float acc = b[c];
    for (int k = 0; k < HD; ++k) acc = fmaf(hrow[k], W[k * NCLS + c], acc);
    out[gid] = acc;
}

extern "C" void kernel_launch(void* const* d_in, const int* in_sizes, int n_in,
                              void* d_out, int out_size, void* d_ws, size_t ws_size,
                              hipStream_t stream) {
    const float* xu = (const float*)d_in[0];
    const int* eu = (const int*)d_in[1];
    const int* nu = (const int*)d_in[2];
    const float* xv = (const float*)d_in[3];
    const int* ev = (const int*)d_in[4];
    const int* nv = (const int*)d_in[5];
    const float* xy = (const float*)d_in[6];
    const int* ey = (const int*)d_in[7];
    const int* ny = (const int*)d_in[8];
    const float* W_enc = (const float*)d_in[9];
    const float* b_enc = (const float*)d_in[10];
    const float* W1 = (const float*)d_in[11];
    const float* b1 = (const float*)d_in[12];
    const float* W2 = (const float*)d_in[13];
    const float* b2 = (const float*)d_in[14];
    const float* W_upd = (const float*)d_in[15];
    const float* b_upd = (const float*)d_in[16];
    const float* W_sp = (const float*)d_in[17];
    const float* b_sp = (const float*)d_in[18];
    const float* W_nx = (const float*)d_in[19];
    const float* b_nx = (const float*)d_in[20];
    const float* W_sem = (const float*)d_in[21];
    const float* b_sem = (const float*)d_in[22];

    const size_t HN = (size_t)3 * N_HITS * HD;  // 11,520,000
    float* ws = (float*)d_ws;
    float* h = ws;                          // [3][N_HITS][HD] fp32
    float* agg = h + HN;                    // [3][N_HITS][HD] fp32 (also "back")
    float* sp = agg + HN;                   // [N_SPS][HD]
    float* inv = sp + (size_t)N_SPS * HD;   // [9 * 30000]: edge-dst | sp | hit
    int* cnt = (int*)(inv + 270000);        // [9 * 30000]
    __bf16* hb = (__bf16*)(cnt + 270000);   // [3][N_HITS][HD] bf16 mirror
    __bf16* W1P = hb + HN;                  // 32768
    __bf16* W2P = W1P + 32768;              // 16384
    __bf16* WuP = W2P + 16384;              // 32768
    __bf16* WnP = WuP + 32768;              // 32768

    // ---- per-call constants: weight pack + segment counts ----
    wprep_kernel<<<448, 256, 0, stream>>>(W1, W2, W_upd, W_nx, W1P, W2P, WuP, WnP);
    hipMemsetAsync(cnt, 0, 270000 * sizeof(int), stream);
    const int* edges[3] = {eu, ev, ey};
    const int* nxs[3] = {nu, nv, ny};
    for (int p = 0; p < 3; ++p) {
        hist_kernel<<<(N_EDGES + 255) / 256, 256, 0, stream>>>(edges[p] + N_EDGES, cnt + p * N_HITS, N_EDGES);
        hist_kernel<<<(N_SPS + 255) / 256, 256, 0, stream>>>(nxs[p] + N_SPS, cnt + 90000 + p * N_SPS, N_SPS);
        hist_kernel<<<(N_SPS + 255) / 256, 256, 0, stream>>>(nxs[p], cnt + 180000 + p * N_HITS, N_SPS);
    }
    inv_kernel<<<(270000 + 255) / 256, 256, 0, stream>>>(cnt, inv, 270000);

    // ---- encoder ----
    enc_kernel<<<(3 * N_HITS * HD + 255) / 256, 256, 0, stream>>>(xu, xv, xy, W_enc, b_enc, h, hb);

    // ---- 3 core iterations ----
    for (int it = 0; it < 3; ++it) {
        // planar conv
        hipMemsetAsync(agg, 0, HN * sizeof(float), stream);
        edge_mfma_kernel<<<dim3((N_EDGES + 63) / 64, 3), 256, 0, stream>>>(
            hb, eu, ev, ey, W1P, b1, W2P, b2, inv, agg);
        update_mfma_kernel<<<dim3((N_HITS + 63) / 64, 3), 256, 0, stream>>>(h, hb, agg, WuP, b_upd);
        // nexus conv
        hipMemsetAsync(sp, 0, (size_t)N_SPS * HD * sizeof(float), stream);
        nx_scatter_kernel<<<(3 * N_SPS * 64) / 256, 256, 0, stream>>>(h, nu, nv, ny, inv + 90000, sp);
        sp_gemm_kernel<<<(N_SPS + 63) / 64, 256, 0, stream>>>(sp, W_sp, b_sp);
        hipMemsetAsync(agg, 0, HN * sizeof(float), stream);
        back_scatter_kernel<<<(3 * N_SPS * 64) / 256, 256, 0, stream>>>(sp, nu, nv, ny, inv + 180000, agg);
        update_mfma_kernel<<<dim3((N_HITS + 63) / 64, 3), 256, 0, stream>>>(h, hb, agg, WnP, b_nx);
    }

    // ---- decoder ----
    dec_kernel<<<(3 * N_HITS * NCLS + 255) / 256, 256, 0, stream>>>(h, W_sem, b_sem, (float*)d_out);
}

// Round 3
// 1345.042 us; speedup vs baseline: 2.2415x; 1.1509x over previous
//
#include <hip/hip_runtime.h>

#define N_HITS 30000
#define N_EDGES 90000
#define N_SPS 30000
#define HD 128
#define NCLS 5

#define PADA 264  // 256 + 8 bf16 pad
#define PADM 136  // 128 + 8

typedef __attribute__((ext_vector_type(8))) __bf16 bf16x8;
typedef __attribute__((ext_vector_type(4))) float floatx4;

__device__ __forceinline__ uint4 cvt8_bf16(float4 a, float4 b) {
    union { __bf16 h[8]; uint4 u; } x;
    x.h[0] = (__bf16)a.x; x.h[1] = (__bf16)a.y; x.h[2] = (__bf16)a.z; x.h[3] = (__bf16)a.w;
    x.h[4] = (__bf16)b.x; x.h[5] = (__bf16)b.y; x.h[6] = (__bf16)b.z; x.h[7] = (__bf16)b.w;
    return x.u;
}

// ---------------- encoder ----------------
__global__ void enc_kernel(const float* __restrict__ xu, const float* __restrict__ xv,
                           const float* __restrict__ xy, const float* __restrict__ W,
                           const float* __restrict__ b, float* __restrict__ h,
                           __bf16* __restrict__ hb) {
    int gid = blockIdx.x * blockDim.x + threadIdx.x;
    if (gid >= 3 * N_HITS * HD) return;
    int j = gid & (HD - 1);
    int n = (gid >> 7) % N_HITS;
    int p = gid / (N_HITS * HD);
    const float* x = (p == 0) ? xu : (p == 1) ? xv : xy;
    float acc = b[j];
#pragma unroll
    for (int k = 0; k < 4; ++k) acc = fmaf(x[n * 4 + k], W[k * HD + j], acc);
    float v = fmaxf(acc, 0.f);
    h[gid] = v;
    hb[gid] = (__bf16)v;
}

// ---------------- histogram / inverse ----------------
__global__ void hist_kernel(const int* __restrict__ idx, int* __restrict__ cnt, int n) {
    int i = blockIdx.x * blockDim.x + threadIdx.x;
    if (i < n) atomicAdd(&cnt[idx[i]], 1);
}

__global__ void inv_kernel(const int* __restrict__ cnt, float* __restrict__ inv, int n) {
    int i = blockIdx.x * blockDim.x + threadIdx.x;
    if (i < n) inv[i] = 1.0f / (float)(cnt[i] > 1 ? cnt[i] : 1);
}

// ---------------- weight pre-pack: fp32 [K][128] -> bf16 B-frag order ----------------
__global__ void wprep_kernel(const float* __restrict__ W1, const float* __restrict__ W2,
                             const float* __restrict__ Wu, const float* __restrict__ Wn,
                             __bf16* __restrict__ W1P, __bf16* __restrict__ W2P,
                             __bf16* __restrict__ WuP, __bf16* __restrict__ WnP) {
    int gid = blockIdx.x * blockDim.x + threadIdx.x;
    if (gid < 32768) {  // W1: 256x128, 8 k-steps
        int idx = gid;
        int j = idx & 7, lane = (idx >> 3) & 63, ks = (idx >> 9) & 7, n = (idx >> 12) & 7;
        int k = ks * 32 + (lane >> 4) * 8 + j, col = n * 16 + (lane & 15);
        W1P[idx] = (__bf16)W1[k * 128 + col];
        return;
    }
    gid -= 32768;
    if (gid < 16384) {  // W2: 128x128, 4 k-steps
        int idx = gid;
        int j = idx & 7, lane = (idx >> 3) & 63, ks = (idx >> 9) & 3, n = (idx >> 11) & 7;
        int k = ks * 32 + (lane >> 4) * 8 + j, col = n * 16 + (lane & 15);
        W2P[idx] = (__bf16)W2[k * 128 + col];
        return;
    }
    gid -= 16384;
    if (gid < 32768) {
        int idx = gid;
        int j = idx & 7, lane = (idx >> 3) & 63, ks = (idx >> 9) & 7, n = (idx >> 12) & 7;
        int k = ks * 32 + (lane >> 4) * 8 + j, col = n * 16 + (lane & 15);
        WuP[idx] = (__bf16)Wu[k * 128 + col];
        return;
    }
    gid -= 32768;
    if (gid < 32768) {
        int idx = gid;
        int j = idx & 7, lane = (idx >> 3) & 63, ks = (idx >> 9) & 7, n = (idx >> 12) & 7;
        int k = ks * 32 + (lane >> 4) * 8 + j, col = n * 16 + (lane & 15);
        WnP[idx] = (__bf16)Wn[k * 128 + col];
    }
}

// ---------------- edge MLP (MFMA): M-tile 128, 4 waves, wave owns 32 cols ----------------
// B-fragments register-resident (loaded once per block); A streamed from LDS.
__launch_bounds__(256)
__global__ void edge_mfma_kernel(const __bf16* __restrict__ hb, const int* __restrict__ eu,
                                 const int* __restrict__ ev, const int* __restrict__ ey,
                                 const __bf16* __restrict__ W1P, const float* __restrict__ b1,
                                 const __bf16* __restrict__ W2P, const float* __restrict__ b2,
                                 const float* __restrict__ invd, float* __restrict__ agg) {
    int p = blockIdx.y;
    const int* e = (p == 0) ? eu : (p == 1) ? ev : ey;
    const __bf16* hbp = hb + (size_t)p * N_HITS * HD;
    float* aggp = agg + (size_t)p * N_HITS * HD;
    const float* invp = invd + p * N_HITS;

    __shared__ __bf16 sA[128 * PADA];  // 67584 B; sM overlays after layer1
    __shared__ int sSrc[128], sDst[128];
    __shared__ float sInv[128];

    int t = threadIdx.x;
    int e0 = blockIdx.x * 128;
    if (t < 128) {
        int ei = e0 + t;
        int s = 0, d = 0; float iv = 0.f;
        if (ei < N_EDGES) { s = e[ei]; d = e[N_EDGES + ei]; iv = invp[d]; }
        sSrc[t] = s; sDst[t] = d; sInv[t] = iv;
    }
    __syncthreads();
    // stage A: 128 rows x [hb[dst](128) | hb[src](128)] bf16, 32 x16B chunks/row
    for (int i = t; i < 4096; i += 256) {
        int row = i >> 5, c = i & 31;
        int node = (c < 16) ? sDst[row] : sSrc[row];
        uint4 v = ((const uint4*)(hbp + (size_t)node * HD))[c & 15];
        *(uint4*)&sA[row * PADA + c * 8] = v;
    }
    __syncthreads();

    int lane = t & 63;
    int wave = t >> 6;
    int lcol = lane & 15;
    int quad = lane >> 4;
    int nt0 = wave * 2;  // this wave's first n-tile (of 8)

    // ---- layer 1: [128x256] @ [256x32-slice] ----
    const bf16x8* w1p = (const bf16x8*)W1P;
    bf16x8 B1[2][8];
#pragma unroll
    for (int nt = 0; nt < 2; ++nt)
#pragma unroll
        for (int ks = 0; ks < 8; ++ks)
            B1[nt][ks] = w1p[((nt0 + nt) * 8 + ks) * 64 + lane];

    floatx4 acc[8][2];
#pragma unroll
    for (int nt = 0; nt < 2; ++nt) {
        float bv = b1[(nt0 + nt) * 16 + lcol];
#pragma unroll
        for (int mt = 0; mt < 8; ++mt) acc[mt][nt] = (floatx4){bv, bv, bv, bv};
    }
#pragma unroll
    for (int mt = 0; mt < 8; ++mt) {
#pragma unroll
        for (int ks = 0; ks < 8; ++ks) {
            bf16x8 a = *(const bf16x8*)&sA[(mt * 16 + lcol) * PADA + ks * 32 + quad * 8];
            acc[mt][0] = __builtin_amdgcn_mfma_f32_16x16x32_bf16(a, B1[0][ks], acc[mt][0], 0, 0, 0);
            acc[mt][1] = __builtin_amdgcn_mfma_f32_16x16x32_bf16(a, B1[1][ks], acc[mt][1], 0, 0, 0);
        }
    }
    __syncthreads();  // all layer1 sA reads complete before overlay
    // relu -> bf16 -> sM (overlaid on sA)
    __bf16* sM = sA;
#pragma unroll
    for (int mt = 0; mt < 8; ++mt)
#pragma unroll
        for (int nt = 0; nt < 2; ++nt)
#pragma unroll
            for (int r = 0; r < 4; ++r) {
                int row = mt * 16 + quad * 4 + r;
                sM[row * PADM + (nt0 + nt) * 16 + lcol] = (__bf16)fmaxf(acc[mt][nt][r], 0.f);
            }
    __syncthreads();

    // ---- layer 2: [128x128] @ [128x32-slice] ----
    const bf16x8* w2p = (const bf16x8*)W2P;
    bf16x8 B2[2][4];
#pragma unroll
    for (int nt = 0; nt < 2; ++nt)
#pragma unroll
        for (int ks = 0; ks < 4; ++ks)
            B2[nt][ks] = w2p[((nt0 + nt) * 4 + ks) * 64 + lane];

    floatx4 acc2[8][2];
#pragma unroll
    for (int nt = 0; nt < 2; ++nt) {
        float bv = b2[(nt0 + nt) * 16 + lcol];
#pragma unroll
        for (int mt = 0; mt < 8; ++mt) acc2[mt][nt] = (floatx4){bv, bv, bv, bv};
    }
#pragma unroll
    for (int mt = 0; mt < 8; ++mt) {
#pragma unroll
        for (int ks = 0; ks < 4; ++ks) {
            bf16x8 a = *(const bf16x8*)&sM[(mt * 16 + lcol) * PADM + ks * 32 + quad * 8];
            acc2[mt][0] = __builtin_amdgcn_mfma_f32_16x16x32_bf16(a, B2[0][ks], acc2[mt][0], 0, 0, 0);
            acc2[mt][1] = __builtin_amdgcn_mfma_f32_16x16x32_bf16(a, B2[1][ks], acc2[mt][1], 0, 0, 0);
        }
    }
    // scatter-add (mean via pre-scaled inv; tail rows have inv=0)
#pragma unroll
    for (int mt = 0; mt < 8; ++mt)
#pragma unroll
        for (int nt = 0; nt < 2; ++nt)
#pragma unroll
            for (int r = 0; r < 4; ++r) {
                int row = mt * 16 + quad * 4 + r;
                float v = acc2[mt][nt][r] * sInv[row];
                unsafeAtomicAdd(&aggp[(size_t)sDst[row] * HD + (nt0 + nt) * 16 + lcol], v);
            }
}

// ---------------- node update (MFMA): M-tile 128, same col-split structure ----------------
__launch_bounds__(256)
__global__ void update_mfma_kernel(float* __restrict__ h, __bf16* __restrict__ hb,
                                   const float* __restrict__ aux,
                                   const __bf16* __restrict__ WP, const float* __restrict__ b) {
    int p = blockIdx.y;
    float* hp = h + (size_t)p * N_HITS * HD;
    __bf16* hbp = hb + (size_t)p * N_HITS * HD;
    const float* ap = aux + (size_t)p * N_HITS * HD;

    __shared__ __bf16 sA[128 * PADA];
    int t = threadIdx.x;
    int n0b = blockIdx.x * 128;
    // stage h half (bf16 mirror)
    for (int i = t; i < 2048; i += 256) {
        int row = i >> 4, c = i & 15;
        int n = n0b + row; if (n >= N_HITS) n = N_HITS - 1;
        uint4 v = ((const uint4*)(hbp + (size_t)n * HD))[c];
        *(uint4*)&sA[row * PADA + c * 8] = v;
    }
    // stage aux half (fp32 -> bf16)
    for (int i = t; i < 2048; i += 256) {
        int row = i >> 4, c = i & 15;
        int n = n0b + row; if (n >= N_HITS) n = N_HITS - 1;
        const float4* src = (const float4*)(ap + (size_t)n * HD + c * 8);
        *(uint4*)&sA[row * PADA + 128 + c * 8] = cvt8_bf16(src[0], src[1]);
    }
    __syncthreads();

    int lane = t & 63;
    int wave = t >> 6;
    int lcol = lane & 15;
    int quad = lane >> 4;
    int nt0 = wave * 2;

    const bf16x8* wp = (const bf16x8*)WP;
    bf16x8 B[2][8];
#pragma unroll
    for (int nt = 0; nt < 2; ++nt)
#pragma unroll
        for (int ks = 0; ks < 8; ++ks)
            B[nt][ks] = wp[((nt0 + nt) * 8 + ks) * 64 + lane];

    floatx4 acc[8][2];
#pragma unroll
    for (int nt = 0; nt < 2; ++nt) {
        float bv = b[(nt0 + nt) * 16 + lcol];
#pragma unroll
        for (int mt = 0; mt < 8; ++mt) acc[mt][nt] = (floatx4){bv, bv, bv, bv};
    }
#pragma unroll
    for (int mt = 0; mt < 8; ++mt) {
#pragma unroll
        for (int ks = 0; ks < 8; ++ks) {
            bf16x8 a = *(const bf16x8*)&sA[(mt * 16 + lcol) * PADA + ks * 32 + quad * 8];
            acc[mt][0] = __builtin_amdgcn_mfma_f32_16x16x32_bf16(a, B[0][ks], acc[mt][0], 0, 0, 0);
            acc[mt][1] = __builtin_amdgcn_mfma_f32_16x16x32_bf16(a, B[1][ks], acc[mt][1], 0, 0, 0);
        }
    }
    // residual write + bf16 mirror
#pragma unroll
    for (int mt = 0; mt < 8; ++mt)
#pragma unroll
        for (int nt = 0; nt < 2; ++nt)
#pragma unroll
            for (int r = 0; r < 4; ++r) {
                int m = n0b + mt * 16 + quad * 4 + r;
                if (m < N_HITS) {
                    size_t o = (size_t)m * HD + (nt0 + nt) * 16 + lcol;
                    float nv = hp[o] + fmaxf(acc[mt][nt][r], 0.f);
                    hp[o] = nv;
                    hbp[o] = (__bf16)nv;
                }
            }
}

// ---------------- fp32 tile-GEMM helper (sp_gemm) ----------------
template <int K>
__device__ __forceinline__ void gemm_tile(const float* sA, const float* __restrict__ W,
                                          const float* __restrict__ b, int cg, int rg,
                                          float acc[8][4]) {
    float4 bb = *(const float4*)(b + (cg << 2));
#pragma unroll
    for (int r = 0; r < 8; ++r) { acc[r][0] = bb.x; acc[r][1] = bb.y; acc[r][2] = bb.z; acc[r][3] = bb.w; }
    for (int k = 0; k < K; k += 4) {
        const float* wp = W + k * HD + (cg << 2);
        float4 w0 = *(const float4*)(wp);
        float4 w1 = *(const float4*)(wp + HD);
        float4 w2 = *(const float4*)(wp + 2 * HD);
        float4 w3 = *(const float4*)(wp + 3 * HD);
#pragma unroll
        for (int r = 0; r < 8; ++r) {
            float4 a = *(const float4*)(sA + (rg * 8 + r) * K + k);
            acc[r][0] = fmaf(a.x, w0.x, acc[r][0]); acc[r][1] = fmaf(a.x, w0.y, acc[r][1]);
            acc[r][2] = fmaf(a.x, w0.z, acc[r][2]); acc[r][3] = fmaf(a.x, w0.w, acc[r][3]);
            acc[r][0] = fmaf(a.y, w1.x, acc[r][0]); acc[r][1] = fmaf(a.y, w1.y, acc[r][1]);
            acc[r][2] = fmaf(a.y, w1.z, acc[r][2]); acc[r][3] = fmaf(a.y, w1.w, acc[r][3]);
            acc[r][0] = fmaf(a.z, w2.x, acc[r][0]); acc[r][1] = fmaf(a.z, w2.y, acc[r][1]);
            acc[r][2] = fmaf(a.z, w2.z, acc[r][2]); acc[r][3] = fmaf(a.z, w2.w, acc[r][3]);
            acc[r][0] = fmaf(a.w, w3.x, acc[r][0]); acc[r][1] = fmaf(a.w, w3.y, acc[r][1]);
            acc[r][2] = fmaf(a.w, w3.z, acc[r][2]); acc[r][3] = fmaf(a.w, w3.w, acc[r][3]);
        }
    }
}

// ---------------- nexus scatter ----------------
__global__ void nx_scatter_kernel(const float* __restrict__ h, const int* __restrict__ nu,
                                  const int* __restrict__ nv, const int* __restrict__ ny,
                                  const float* __restrict__ invsp, float* __restrict__ sp) {
    int gt = blockIdx.x * blockDim.x + threadIdx.x;
    int wid = gt >> 6;
    int lane = gt & 63;
    if (wid >= 3 * N_SPS) return;
    int p = wid / N_SPS;
    int i = wid - p * N_SPS;
    const int* nx = (p == 0) ? nu : (p == 1) ? nv : ny;
    int hit = nx[i];
    int spid = nx[N_SPS + i];
    float s = invsp[p * N_SPS + spid];
    const float* hrow = h + (size_t)(p * N_HITS + hit) * HD;
    float* srow = sp + (size_t)spid * HD;
    unsafeAtomicAdd(&srow[lane], hrow[lane] * s);
    unsafeAtomicAdd(&srow[lane + 64], hrow[lane + 64] * s);
}

// ---------------- sp = relu(sp @ W_sp + b_sp) ----------------
__launch_bounds__(256)
__global__ void sp_gemm_kernel(float* __restrict__ sp, const float* __restrict__ W,
                               const float* __restrict__ b) {
    __shared__ float sA[64 * 128];
    int t = threadIdx.x;
    int n0 = blockIdx.x * 64;
    for (int i = t; i < 64 * 32; i += 256) {
        int row = i >> 5, q = i & 31;
        int n = n0 + row; if (n >= N_SPS) n = N_SPS - 1;
        *(float4*)(&sA[row * 128 + q * 4]) = *(const float4*)(sp + (size_t)n * HD + q * 4);
    }
    __syncthreads();
    int cg = t & 31, rg = t >> 5;
    float acc[8][4];
    gemm_tile<128>(sA, W, b, cg, rg, acc);
#pragma unroll
    for (int r = 0; r < 8; ++r) {
        int n = n0 + rg * 8 + r;
        if (n < N_SPS) {
            float4 v;
            v.x = fmaxf(acc[r][0], 0.f); v.y = fmaxf(acc[r][1], 0.f);
            v.z = fmaxf(acc[r][2], 0.f); v.w = fmaxf(acc[r][3], 0.f);
            *(float4*)(sp + (size_t)n * HD + cg * 4) = v;
        }
    }
}

// ---------------- back scatter ----------------
__global__ void back_scatter_kernel(const float* __restrict__ sp, const int* __restrict__ nu,
                                    const int* __restrict__ nv, const int* __restrict__ ny,
                                    const float* __restrict__ invhit, float* __restrict__ back) {
    int gt = blockIdx.x * blockDim.x + threadIdx.x;
    int wid = gt >> 6;
    int lane = gt & 63;
    if (wid >= 3 * N_SPS) return;
    int p = wid / N_SPS;
    int i = wid - p * N_SPS;
    const int* nx = (p == 0) ? nu : (p == 1) ? nv : ny;
    int hit = nx[i];
    int spid = nx[N_SPS + i];
    float s = invhit[p * N_HITS + hit];
    const float* srow = sp + (size_t)spid * HD;
    float* brow = back + (size_t)(p * N_HITS + hit) * HD;
    unsafeAtomicAdd(&brow[lane], srow[lane] * s);
    unsafeAtomicAdd(&brow[lane + 64], srow[lane + 64] * s);
}

// ---------------- decoder ----------------
__global__ void dec_kernel(const float* __restrict__ h, const float* __restrict__ W,
                           const float* __restrict__ b, float* __restrict__ out) {
    int gid = blockIdx.x * blockDim.x + threadIdx.x;
    if (gid >= 3 * N_HITS * NCLS) return;
    int c = gid % NCLS;
    int n = gid / NCLS;
    const float* hrow = h + (size_t)n * HD;
    float acc = b[c];
    for (int k = 0; k < HD; ++k) acc = fmaf(hrow[k], W[k * NCLS + c], acc);
    out[gid] = acc;
}

extern "C" void kernel_launch(void* const* d_in, const int* in_sizes, int n_in,
                              void* d_out, int out_size, void* d_ws, size_t ws_size,
                              hipStream_t stream) {
    const float* xu = (const float*)d_in[0];
    const int* eu = (const int*)d_in[1];
    const int* nu = (const int*)d_in[2];
    const float* xv = (const float*)d_in[3];
    const int* ev = (const int*)d_in[4];
    const int* nv = (const int*)d_in[5];
    const float* xy = (const float*)d_in[6];
    const int* ey = (const int*)d_in[7];
    const int* ny = (const int*)d_in[8];
    const float* W_enc = (const float*)d_in[9];
    const float* b_enc = (const float*)d_in[10];
    const float* W1 = (const float*)d_in[11];
    const float* b1 = (const float*)d_in[12];
    const float* W2 = (const float*)d_in[13];
    const float* b2 = (const float*)d_in[14];
    const float* W_upd = (const float*)d_in[15];
    const float* b_upd = (const float*)d_in[16];
    const float* W_sp = (const float*)d_in[17];
    const float* b_sp = (const float*)d_in[18];
    const float* W_nx = (const float*)d_in[19];
    const float* b_nx = (const float*)d_in[20];
    const float* W_sem = (const float*)d_in[21];
    const float* b_sem = (const float*)d_in[22];

    const size_t HN = (size_t)3 * N_HITS * HD;
    float* ws = (float*)d_ws;
    float* h = ws;
    float* agg = h + HN;
    float* sp = agg + HN;
    float* inv = sp + (size_t)N_SPS * HD;
    int* cnt = (int*)(inv + 270000);
    __bf16* hb = (__bf16*)(cnt + 270000);
    __bf16* W1P = hb + HN;
    __bf16* W2P = W1P + 32768;
    __bf16* WuP = W2P + 16384;
    __bf16* WnP = WuP + 32768;

    wprep_kernel<<<448, 256, 0, stream>>>(W1, W2, W_upd, W_nx, W1P, W2P, WuP, WnP);
    hipMemsetAsync(cnt, 0, 270000 * sizeof(int), stream);
    const int* edges[3] = {eu, ev, ey};
    const int* nxs[3] = {nu, nv, ny};
    for (int p = 0; p < 3; ++p) {
        hist_kernel<<<(N_EDGES + 255) / 256, 256, 0, stream>>>(edges[p] + N_EDGES, cnt + p * N_HITS, N_EDGES);
        hist_kernel<<<(N_SPS + 255) / 256, 256, 0, stream>>>(nxs[p] + N_SPS, cnt + 90000 + p * N_SPS, N_SPS);
        hist_kernel<<<(N_SPS + 255) / 256, 256, 0, stream>>>(nxs[p], cnt + 180000 + p * N_HITS, N_SPS);
    }
    inv_kernel<<<(270000 + 255) / 256, 256, 0, stream>>>(cnt, inv, 270000);

    enc_kernel<<<(3 * N_HITS * HD + 255) / 256, 256, 0, stream>>>(xu, xv, xy, W_enc, b_enc, h, hb);

    for (int it = 0; it < 3; ++it) {
        hipMemsetAsync(agg, 0, HN * sizeof(float), stream);
        edge_mfma_kernel<<<dim3((N_EDGES + 127) / 128, 3), 256, 0, stream>>>(
            hb, eu, ev, ey, W1P, b1, W2P, b2, inv, agg);
        update_mfma_kernel<<<dim3((N_HITS + 127) / 128, 3), 256, 0, stream>>>(h, hb, agg, WuP, b_upd);
        hipMemsetAsync(sp, 0, (size_t)N_SPS * HD * sizeof(float), stream);
        nx_scatter_kernel<<<(3 * N_SPS * 64) / 256, 256, 0, stream>>>(h, nu, nv, ny, inv + 90000, sp);
        sp_gemm_kernel<<<(N_SPS + 63) / 64, 256, 0, stream>>>(sp, W_sp, b_sp);
        hipMemsetAsync(agg, 0, HN * sizeof(float), stream);
        back_scatter_kernel<<<(3 * N_SPS * 64) / 256, 256, 0, stream>>>(sp, nu, nv, ny, inv + 180000, agg);
        update_mfma_kernel<<<dim3((N_HITS + 127) / 128, 3), 256, 0, stream>>>(h, hb, agg, WnP, b_nx);
    }

    dec_kernel<<<(3 * N_HITS * NCLS + 255) / 256, 256, 0, stream>>>(h, W_sem, b_sem, (float*)d_out);
}

// Round 5
// 916.836 us; speedup vs baseline: 3.2884x; 1.4670x over previous
//
#include <hip/hip_runtime.h>
#include <hip/hip_fp16.h>

#define N_HITS 30000
#define N_EDGES 90000
#define N_SPS 30000
#define HD 128
#define NCLS 5

#define PADM 136  // 128 + 8 bf16 pad -> benign bank pattern for ds_read_b128

typedef __attribute__((ext_vector_type(8))) __bf16 bf16x8;
typedef __attribute__((ext_vector_type(4))) float floatx4;

__device__ __forceinline__ void pk_add_f16(__half* addr, float a, float b) {
    // packed f16 atomic add (global_atomic_pk_add_f16) via HIP unsafe atomics
    unsafeAtomicAdd((__half2*)addr, __halves2half2(__float2half(a), __float2half(b)));
}

__device__ __forceinline__ uint4 cvt8_h2b(uint4 raw) {
    union { uint4 u; __half h[8]; } in; in.u = raw;
    union { __bf16 b[8]; uint4 u; } out;
#pragma unroll
    for (int k = 0; k < 8; ++k) out.b[k] = (__bf16)__half2float(in.h[k]);
    return out.u;
}

// ---------------- encoder ----------------
__global__ void enc_kernel(const float* __restrict__ xu, const float* __restrict__ xv,
                           const float* __restrict__ xy, const float* __restrict__ W,
                           const float* __restrict__ b, float* __restrict__ h,
                           __bf16* __restrict__ hb) {
    int gid = blockIdx.x * blockDim.x + threadIdx.x;
    if (gid >= 3 * N_HITS * HD) return;
    int j = gid & (HD - 1);
    int n = (gid >> 7) % N_HITS;
    int p = gid / (N_HITS * HD);
    const float* x = (p == 0) ? xu : (p == 1) ? xv : xy;
    float acc = b[j];
#pragma unroll
    for (int k = 0; k < 4; ++k) acc = fmaf(x[n * 4 + k], W[k * HD + j], acc);
    float v = fmaxf(acc, 0.f);
    h[gid] = v;
    hb[gid] = (__bf16)v;
}

// ---------------- histogram / inverse ----------------
__global__ void hist_kernel(const int* __restrict__ idx, int* __restrict__ cnt, int n) {
    int i = blockIdx.x * blockDim.x + threadIdx.x;
    if (i < n) atomicAdd(&cnt[idx[i]], 1);
}

__global__ void inv_kernel(const int* __restrict__ cnt, float* __restrict__ inv, int n) {
    int i = blockIdx.x * blockDim.x + threadIdx.x;
    if (i < n) inv[i] = 1.0f / (float)(cnt[i] > 1 ? cnt[i] : 1);
}

// ---------------- weight pre-pack: fp32 [K][128] -> bf16 B-frag order ----------------
__global__ void wprep_kernel(const float* __restrict__ W1, const float* __restrict__ W2,
                             const float* __restrict__ Wu, const float* __restrict__ Wn,
                             __bf16* __restrict__ W1P, __bf16* __restrict__ W2P,
                             __bf16* __restrict__ WuP, __bf16* __restrict__ WnP) {
    int gid = blockIdx.x * blockDim.x + threadIdx.x;
    if (gid < 32768) {  // W1: 256x128, 8 k-steps
        int idx = gid;
        int j = idx & 7, lane = (idx >> 3) & 63, ks = (idx >> 9) & 7, n = (idx >> 12) & 7;
        int k = ks * 32 + (lane >> 4) * 8 + j, col = n * 16 + (lane & 15);
        W1P[idx] = (__bf16)W1[k * 128 + col];
        return;
    }
    gid -= 32768;
    if (gid < 16384) {  // W2: 128x128, 4 k-steps
        int idx = gid;
        int j = idx & 7, lane = (idx >> 3) & 63, ks = (idx >> 9) & 3, n = (idx >> 11) & 7;
        int k = ks * 32 + (lane >> 4) * 8 + j, col = n * 16 + (lane & 15);
        W2P[idx] = (__bf16)W2[k * 128 + col];
        return;
    }
    gid -= 16384;
    if (gid < 32768) {
        int idx = gid;
        int j = idx & 7, lane = (idx >> 3) & 63, ks = (idx >> 9) & 7, n = (idx >> 12) & 7;
        int k = ks * 32 + (lane >> 4) * 8 + j, col = n * 16 + (lane & 15);
        WuP[idx] = (__bf16)Wu[k * 128 + col];
        return;
    }
    gid -= 32768;
    if (gid < 32768) {
        int idx = gid;
        int j = idx & 7, lane = (idx >> 3) & 63, ks = (idx >> 9) & 7, n = (idx >> 12) & 7;
        int k = ks * 32 + (lane >> 4) * 8 + j, col = n * 16 + (lane & 15);
        WnP[idx] = (__bf16)Wn[k * 128 + col];
    }
}

// ---------------- edge MLP (MFMA): M=128, split-K staging, f16 packed-atomic scatter ----------------
__launch_bounds__(256, 4)
__global__ void edge_mfma_kernel(const __bf16* __restrict__ hb, const int* __restrict__ eu,
                                 const int* __restrict__ ev, const int* __restrict__ ey,
                                 const __bf16* __restrict__ W1P, const float* __restrict__ b1,
                                 const __bf16* __restrict__ W2P, const float* __restrict__ b2,
                                 const float* __restrict__ invd, __half* __restrict__ agg) {
    int p = blockIdx.y;
    const int* e = (p == 0) ? eu : (p == 1) ? ev : ey;
    const __bf16* hbp = hb + (size_t)p * N_HITS * HD;
    __half* aggp = agg + (size_t)p * N_HITS * HD;
    const float* invp = invd + p * N_HITS;

    __shared__ __bf16 sA[128 * PADM];  // 34816 B; reused: dst-half, src-half, relu tile
    __shared__ int sSrc[128], sDst[128];
    __shared__ float sInv[128];

    int t = threadIdx.x;
    int e0 = blockIdx.x * 128;
    if (t < 128) {
        int ei = e0 + t;
        int s = 0, d = 0; float iv = 0.f;
        if (ei < N_EDGES) { s = e[ei]; d = e[N_EDGES + ei]; iv = invp[d]; }
        sSrc[t] = s; sDst[t] = d; sInv[t] = iv;
    }
    __syncthreads();

    int lane = t & 63;
    int wave = t >> 6;
    int lcol = lane & 15;
    int quad = lane >> 4;
    int nt0 = wave * 2;  // wave's first n-tile (of 8)

    const bf16x8* w1p = (const bf16x8*)W1P;
    floatx4 acc[8][2];
#pragma unroll
    for (int nt = 0; nt < 2; ++nt) {
        float bv = b1[(nt0 + nt) * 16 + lcol];
#pragma unroll
        for (int mt = 0; mt < 8; ++mt) acc[mt][nt] = (floatx4){bv, bv, bv, bv};
    }

    // ---- phase 1: dst half (K = 0..127) ----
    for (int i = t; i < 2048; i += 256) {
        int row = i >> 4, c = i & 15;
        uint4 v = ((const uint4*)(hbp + (size_t)sDst[row] * HD))[c];
        *(uint4*)&sA[row * PADM + c * 8] = v;
    }
    __syncthreads();
    {
        bf16x8 B1[2][4];
#pragma unroll
        for (int nt = 0; nt < 2; ++nt)
#pragma unroll
            for (int ks = 0; ks < 4; ++ks)
                B1[nt][ks] = w1p[((nt0 + nt) * 8 + ks) * 64 + lane];
#pragma unroll
        for (int mt = 0; mt < 8; ++mt)
#pragma unroll
            for (int ks = 0; ks < 4; ++ks) {
                bf16x8 a = *(const bf16x8*)&sA[(mt * 16 + lcol) * PADM + ks * 32 + quad * 8];
                acc[mt][0] = __builtin_amdgcn_mfma_f32_16x16x32_bf16(a, B1[0][ks], acc[mt][0], 0, 0, 0);
                acc[mt][1] = __builtin_amdgcn_mfma_f32_16x16x32_bf16(a, B1[1][ks], acc[mt][1], 0, 0, 0);
            }
    }
    __syncthreads();
    // ---- phase 2: src half (K = 128..255) ----
    for (int i = t; i < 2048; i += 256) {
        int row = i >> 4, c = i & 15;
        uint4 v = ((const uint4*)(hbp + (size_t)sSrc[row] * HD))[c];
        *(uint4*)&sA[row * PADM + c * 8] = v;
    }
    __syncthreads();
    {
        bf16x8 B1[2][4];
#pragma unroll
        for (int nt = 0; nt < 2; ++nt)
#pragma unroll
            for (int ks = 0; ks < 4; ++ks)
                B1[nt][ks] = w1p[((nt0 + nt) * 8 + 4 + ks) * 64 + lane];
#pragma unroll
        for (int mt = 0; mt < 8; ++mt)
#pragma unroll
            for (int ks = 0; ks < 4; ++ks) {
                bf16x8 a = *(const bf16x8*)&sA[(mt * 16 + lcol) * PADM + ks * 32 + quad * 8];
                acc[mt][0] = __builtin_amdgcn_mfma_f32_16x16x32_bf16(a, B1[0][ks], acc[mt][0], 0, 0, 0);
                acc[mt][1] = __builtin_amdgcn_mfma_f32_16x16x32_bf16(a, B1[1][ks], acc[mt][1], 0, 0, 0);
            }
    }
    __syncthreads();
    // relu -> bf16 -> same buffer (m tile, 128 cols @ stride PADM)
#pragma unroll
    for (int mt = 0; mt < 8; ++mt)
#pragma unroll
        for (int nt = 0; nt < 2; ++nt)
#pragma unroll
            for (int r = 0; r < 4; ++r) {
                int row = mt * 16 + quad * 4 + r;
                sA[row * PADM + (nt0 + nt) * 16 + lcol] = (__bf16)fmaxf(acc[mt][nt][r], 0.f);
            }
    __syncthreads();

    // ---- layer 2: [128x128] @ [128x32-slice] ----
    const bf16x8* w2p = (const bf16x8*)W2P;
    bf16x8 B2[2][4];
#pragma unroll
    for (int nt = 0; nt < 2; ++nt)
#pragma unroll
        for (int ks = 0; ks < 4; ++ks)
            B2[nt][ks] = w2p[((nt0 + nt) * 4 + ks) * 64 + lane];

    floatx4 acc2[8][2];
#pragma unroll
    for (int nt = 0; nt < 2; ++nt) {
        float bv = b2[(nt0 + nt) * 16 + lcol];
#pragma unroll
        for (int mt = 0; mt < 8; ++mt) acc2[mt][nt] = (floatx4){bv, bv, bv, bv};
    }
#pragma unroll
    for (int mt = 0; mt < 8; ++mt)
#pragma unroll
        for (int ks = 0; ks < 4; ++ks) {
            bf16x8 a = *(const bf16x8*)&sA[(mt * 16 + lcol) * PADM + ks * 32 + quad * 8];
            acc2[mt][0] = __builtin_amdgcn_mfma_f32_16x16x32_bf16(a, B2[0][ks], acc2[mt][0], 0, 0, 0);
            acc2[mt][1] = __builtin_amdgcn_mfma_f32_16x16x32_bf16(a, B2[1][ks], acc2[mt][1], 0, 0, 0);
        }

    // ---- scatter: packed f16 atomics, adjacent-col pairing via shfl_xor(1) ----
    bool odd = (lcol & 1) != 0;
#pragma unroll
    for (int mt = 0; mt < 8; ++mt)
#pragma unroll
        for (int r = 0; r < 4; ++r) {
            int row = mt * 16 + quad * 4 + r;
            float s = sInv[row];
            float v0 = acc2[mt][0][r] * s;
            float v1 = acc2[mt][1][r] * s;
            float p0 = __shfl_xor(v0, 1);
            float p1 = __shfl_xor(v1, 1);
            float av = odd ? p1 : v0;
            float bv = odd ? v1 : p0;
            int col = nt0 * 16 + (odd ? 15 + lcol : lcol);
            pk_add_f16(&aggp[(size_t)sDst[row] * HD + col], av, bv);
        }
}

// ---------------- node update (MFMA): split-K, aux is f16, h += relu([h|aux]@W+b) ----------------
__launch_bounds__(256, 4)
__global__ void update_mfma_kernel(float* __restrict__ h, __bf16* __restrict__ hb,
                                   const __half* __restrict__ aux,
                                   const __bf16* __restrict__ WP, const float* __restrict__ b) {
    int p = blockIdx.y;
    float* hp = h + (size_t)p * N_HITS * HD;
    __bf16* hbp = hb + (size_t)p * N_HITS * HD;
    const __half* ap = aux + (size_t)p * N_HITS * HD;

    __shared__ __bf16 sA[128 * PADM];
    int t = threadIdx.x;
    int n0b = blockIdx.x * 128;

    int lane = t & 63;
    int wave = t >> 6;
    int lcol = lane & 15;
    int quad = lane >> 4;
    int nt0 = wave * 2;

    const bf16x8* wp = (const bf16x8*)WP;
    floatx4 acc[8][2];
#pragma unroll
    for (int nt = 0; nt < 2; ++nt) {
        float bv = b[(nt0 + nt) * 16 + lcol];
#pragma unroll
        for (int mt = 0; mt < 8; ++mt) acc[mt][nt] = (floatx4){bv, bv, bv, bv};
    }

    // ---- phase 1: h half (bf16 mirror, contiguous rows) ----
    for (int i = t; i < 2048; i += 256) {
        int row = i >> 4, c = i & 15;
        int n = n0b + row; if (n >= N_HITS) n = N_HITS - 1;
        uint4 v = ((const uint4*)(hbp + (size_t)n * HD))[c];
        *(uint4*)&sA[row * PADM + c * 8] = v;
    }
    __syncthreads();
    {
        bf16x8 B[2][4];
#pragma unroll
        for (int nt = 0; nt < 2; ++nt)
#pragma unroll
            for (int ks = 0; ks < 4; ++ks)
                B[nt][ks] = wp[((nt0 + nt) * 8 + ks) * 64 + lane];
#pragma unroll
        for (int mt = 0; mt < 8; ++mt)
#pragma unroll
            for (int ks = 0; ks < 4; ++ks) {
                bf16x8 a = *(const bf16x8*)&sA[(mt * 16 + lcol) * PADM + ks * 32 + quad * 8];
                acc[mt][0] = __builtin_amdgcn_mfma_f32_16x16x32_bf16(a, B[0][ks], acc[mt][0], 0, 0, 0);
                acc[mt][1] = __builtin_amdgcn_mfma_f32_16x16x32_bf16(a, B[1][ks], acc[mt][1], 0, 0, 0);
            }
    }
    __syncthreads();
    // ---- phase 2: aux half (f16 -> bf16) ----
    for (int i = t; i < 2048; i += 256) {
        int row = i >> 4, c = i & 15;
        int n = n0b + row; if (n >= N_HITS) n = N_HITS - 1;
        uint4 raw = ((const uint4*)(ap + (size_t)n * HD))[c];
        *(uint4*)&sA[row * PADM + c * 8] = cvt8_h2b(raw);
    }
    __syncthreads();
    {
        bf16x8 B[2][4];
#pragma unroll
        for (int nt = 0; nt < 2; ++nt)
#pragma unroll
            for (int ks = 0; ks < 4; ++ks)
                B[nt][ks] = wp[((nt0 + nt) * 8 + 4 + ks) * 64 + lane];
#pragma unroll
        for (int mt = 0; mt < 8; ++mt)
#pragma unroll
            for (int ks = 0; ks < 4; ++ks) {
                bf16x8 a = *(const bf16x8*)&sA[(mt * 16 + lcol) * PADM + ks * 32 + quad * 8];
                acc[mt][0] = __builtin_amdgcn_mfma_f32_16x16x32_bf16(a, B[0][ks], acc[mt][0], 0, 0, 0);
                acc[mt][1] = __builtin_amdgcn_mfma_f32_16x16x32_bf16(a, B[1][ks], acc[mt][1], 0, 0, 0);
            }
    }
    // residual write + bf16 mirror
#pragma unroll
    for (int mt = 0; mt < 8; ++mt)
#pragma unroll
        for (int nt = 0; nt < 2; ++nt)
#pragma unroll
            for (int r = 0; r < 4; ++r) {
                int m = n0b + mt * 16 + quad * 4 + r;
                if (m < N_HITS) {
                    size_t o = (size_t)m * HD + (nt0 + nt) * 16 + lcol;
                    float nv = hp[o] + fmaxf(acc[mt][nt][r], 0.f);
                    hp[o] = nv;
                    hbp[o] = (__bf16)nv;
                }
            }
}

// ---------------- fp32 tile-GEMM helper (sp_gemm) ----------------
__device__ __forceinline__ void gemm_tile128(const float* sA, const float* __restrict__ W,
                                             const float* __restrict__ b, int cg, int rg,
                                             float acc[8][4]) {
    float4 bb = *(const float4*)(b + (cg << 2));
#pragma unroll
    for (int r = 0; r < 8; ++r) { acc[r][0] = bb.x; acc[r][1] = bb.y; acc[r][2] = bb.z; acc[r][3] = bb.w; }
    for (int k = 0; k < 128; k += 4) {
        const float* wp = W + k * HD + (cg << 2);
        float4 w0 = *(const float4*)(wp);
        float4 w1 = *(const float4*)(wp + HD);
        float4 w2 = *(const float4*)(wp + 2 * HD);
        float4 w3 = *(const float4*)(wp + 3 * HD);
#pragma unroll
        for (int r = 0; r < 8; ++r) {
            float4 a = *(const float4*)(sA + (rg * 8 + r) * 128 + k);
            acc[r][0] = fmaf(a.x, w0.x, acc[r][0]); acc[r][1] = fmaf(a.x, w0.y, acc[r][1]);
            acc[r][2] = fmaf(a.x, w0.z, acc[r][2]); acc[r][3] = fmaf(a.x, w0.w, acc[r][3]);
            acc[r][0] = fmaf(a.y, w1.x, acc[r][0]); acc[r][1] = fmaf(a.y, w1.y, acc[r][1]);
            acc[r][2] = fmaf(a.y, w1.z, acc[r][2]); acc[r][3] = fmaf(a.y, w1.w, acc[r][3]);
            acc[r][0] = fmaf(a.z, w2.x, acc[r][0]); acc[r][1] = fmaf(a.z, w2.y, acc[r][1]);
            acc[r][2] = fmaf(a.z, w2.z, acc[r][2]); acc[r][3] = fmaf(a.z, w2.w, acc[r][3]);
            acc[r][0] = fmaf(a.w, w3.x, acc[r][0]); acc[r][1] = fmaf(a.w, w3.y, acc[r][1]);
            acc[r][2] = fmaf(a.w, w3.z, acc[r][2]); acc[r][3] = fmaf(a.w, w3.w, acc[r][3]);
        }
    }
}

// ---------------- nexus scatter: sp[spid] += h[hit]*inv (f16 packed atomics) ----------------
__global__ void nx_scatter_kernel(const float* __restrict__ h, const int* __restrict__ nu,
                                  const int* __restrict__ nv, const int* __restrict__ ny,
                                  const float* __restrict__ invsp, __half* __restrict__ sp) {
    int gt = blockIdx.x * blockDim.x + threadIdx.x;
    int wid = gt >> 6;
    int lane = gt & 63;
    if (wid >= 3 * N_SPS) return;
    int p = wid / N_SPS;
    int i = wid - p * N_SPS;
    const int* nx = (p == 0) ? nu : (p == 1) ? nv : ny;
    int hit = nx[i];
    int spid = nx[N_SPS + i];
    float s = invsp[p * N_SPS + spid];
    const float* hrow = h + (size_t)(p * N_HITS + hit) * HD;
    __half* srow = sp + (size_t)spid * HD;
    float2 hv = *(const float2*)(hrow + 2 * lane);
    pk_add_f16(&srow[2 * lane], hv.x * s, hv.y * s);
}

// ---------------- sp = relu(sp @ W_sp + b_sp), f16 in/out, fp32 compute ----------------
__launch_bounds__(256)
__global__ void sp_gemm_kernel(__half* __restrict__ spf, const float* __restrict__ W,
                               const float* __restrict__ b) {
    __shared__ float sA[64 * 128];
    int t = threadIdx.x;
    int n0 = blockIdx.x * 64;
    for (int i = t; i < 1024; i += 256) {
        int row = i >> 4, c = i & 15;
        int n = n0 + row; if (n >= N_SPS) n = N_SPS - 1;
        union { uint4 u; __half hh[8]; } in;
        in.u = ((const uint4*)(spf + (size_t)n * HD))[c];
#pragma unroll
        for (int k = 0; k < 8; ++k) sA[row * 128 + c * 8 + k] = __half2float(in.hh[k]);
    }
    __syncthreads();
    int cg = t & 31, rg = t >> 5;
    float acc[8][4];
    gemm_tile128(sA, W, b, cg, rg, acc);
#pragma unroll
    for (int r = 0; r < 8; ++r) {
        int n = n0 + rg * 8 + r;
        if (n < N_SPS) {
            union { ushort s[4]; uint2 u; } o;
            o.s[0] = __half_as_ushort(__float2half(fmaxf(acc[r][0], 0.f)));
            o.s[1] = __half_as_ushort(__float2half(fmaxf(acc[r][1], 0.f)));
            o.s[2] = __half_as_ushort(__float2half(fmaxf(acc[r][2], 0.f)));
            o.s[3] = __half_as_ushort(__float2half(fmaxf(acc[r][3], 0.f)));
            *(uint2*)(spf + (size_t)n * HD + cg * 4) = o.u;
        }
    }
}

// ---------------- back scatter: back[hit] += sp[spid]*inv (f16 packed atomics) ----------------
__global__ void back_scatter_kernel(const __half* __restrict__ sp, const int* __restrict__ nu,
                                    const int* __restrict__ nv, const int* __restrict__ ny,
                                    const float* __restrict__ invhit, __half* __restrict__ back) {
    int gt = blockIdx.x * blockDim.x + threadIdx.x;
    int wid = gt >> 6;
    int lane = gt & 63;
    if (wid >= 3 * N_SPS) return;
    int p = wid / N_SPS;
    int i = wid - p * N_SPS;
    const int* nx = (p == 0) ? nu : (p == 1) ? nv : ny;
    int hit = nx[i];
    int spid = nx[N_SPS + i];
    float s = invhit[p * N_HITS + hit];
    const __half* srow = sp + (size_t)spid * HD;
    __half* brow = back + (size_t)(p * N_HITS + hit) * HD;
    float2 f = __half22float2(*(const __half2*)&srow[2 * lane]);
    pk_add_f16(&brow[2 * lane], f.x * s, f.y * s);
}

// ---------------- decoder ----------------
__global__ void dec_kernel(const float* __restrict__ h, const float* __restrict__ W,
                           const float* __restrict__ b, float* __restrict__ out) {
    int gid = blockIdx.x * blockDim.x + threadIdx.x;
    if (gid >= 3 * N_HITS * NCLS) return;
    int c = gid % NCLS;
    int n = gid / NCLS;
    const float* hrow = h + (size_t)n * HD;
    float acc = b[c];
    for (int k = 0; k < HD; ++k) acc = fmaf(hrow[k], W[k * NCLS + c], acc);
    out[gid] = acc;
}

extern "C" void kernel_launch(void* const* d_in, const int* in_sizes, int n_in,
                              void* d_out, int out_size, void* d_ws, size_t ws_size,
                              hipStream_t stream) {
    const float* xu = (const float*)d_in[0];
    const int* eu = (const int*)d_in[1];
    const int* nu = (const int*)d_in[2];
    const float* xv = (const float*)d_in[3];
    const int* ev = (const int*)d_in[4];
    const int* nv = (const int*)d_in[5];
    const float* xy = (const float*)d_in[6];
    const int* ey = (const int*)d_in[7];
    const int* ny = (const int*)d_in[8];
    const float* W_enc = (const float*)d_in[9];
    const float* b_enc = (const float*)d_in[10];
    const float* W1 = (const float*)d_in[11];
    const float* b1 = (const float*)d_in[12];
    const float* W2 = (const float*)d_in[13];
    const float* b2 = (const float*)d_in[14];
    const float* W_upd = (const float*)d_in[15];
    const float* b_upd = (const float*)d_in[16];
    const float* W_sp = (const float*)d_in[17];
    const float* b_sp = (const float*)d_in[18];
    const float* W_nx = (const float*)d_in[19];
    const float* b_nx = (const float*)d_in[20];
    const float* W_sem = (const float*)d_in[21];
    const float* b_sem = (const float*)d_in[22];

    const size_t HN = (size_t)3 * N_HITS * HD;  // 11,520,000
    float* ws = (float*)d_ws;
    float* h = ws;                              // fp32 [3][N_HITS][HD]
    __bf16* hb = (__bf16*)(h + HN);             // bf16 mirror
    __half* agg = (__half*)(hb + HN);           // f16 [3][N_HITS][HD] (planar agg / nexus back)
    __half* sp = agg + HN;                      // f16 [N_SPS][HD]
    float* inv = (float*)(sp + (size_t)N_SPS * HD);  // [9*30000]: edge-dst | sp | hit
    int* cnt = (int*)(inv + 270000);
    __bf16* W1P = (__bf16*)(cnt + 270000);
    __bf16* W2P = W1P + 32768;
    __bf16* WuP = W2P + 16384;
    __bf16* WnP = WuP + 32768;

    wprep_kernel<<<448, 256, 0, stream>>>(W1, W2, W_upd, W_nx, W1P, W2P, WuP, WnP);
    (void)hipMemsetAsync(cnt, 0, 270000 * sizeof(int), stream);
    const int* edges[3] = {eu, ev, ey};
    const int* nxs[3] = {nu, nv, ny};
    for (int p = 0; p < 3; ++p) {
        hist_kernel<<<(N_EDGES + 255) / 256, 256, 0, stream>>>(edges[p] + N_EDGES, cnt + p * N_HITS, N_EDGES);
        hist_kernel<<<(N_SPS + 255) / 256, 256, 0, stream>>>(nxs[p] + N_SPS, cnt + 90000 + p * N_SPS, N_SPS);
        hist_kernel<<<(N_SPS + 255) / 256, 256, 0, stream>>>(nxs[p], cnt + 180000 + p * N_HITS, N_SPS);
    }
    inv_kernel<<<(270000 + 255) / 256, 256, 0, stream>>>(cnt, inv, 270000);

    enc_kernel<<<(3 * N_HITS * HD + 255) / 256, 256, 0, stream>>>(xu, xv, xy, W_enc, b_enc, h, hb);

    for (int it = 0; it < 3; ++it) {
        (void)hipMemsetAsync(agg, 0, HN * sizeof(__half), stream);
        edge_mfma_kernel<<<dim3((N_EDGES + 127) / 128, 3), 256, 0, stream>>>(
            hb, eu, ev, ey, W1P, b1, W2P, b2, inv, agg);
        update_mfma_kernel<<<dim3((N_HITS + 127) / 128, 3), 256, 0, stream>>>(h, hb, agg, WuP, b_upd);
        (void)hipMemsetAsync(sp, 0, (size_t)N_SPS * HD * sizeof(__half), stream);
        nx_scatter_kernel<<<(3 * N_SPS * 64) / 256, 256, 0, stream>>>(h, nu, nv, ny, inv + 90000, sp);
        sp_gemm_kernel<<<(N_SPS + 63) / 64, 256, 0, stream>>>(sp, W_sp, b_sp);
        (void)hipMemsetAsync(agg, 0, HN * sizeof(__half), stream);
        back_scatter_kernel<<<(3 * N_SPS * 64) / 256, 256, 0, stream>>>(sp, nu, nv, ny, inv + 180000, agg);
        update_mfma_kernel<<<dim3((N_HITS + 127) / 128, 3), 256, 0, stream>>>(h, hb, agg, WnP, b_nx);
    }

    dec_kernel<<<(3 * N_HITS * NCLS + 255) / 256, 256, 0, stream>>>(h, W_sem, b_sem, (float*)d_out);
}